// Round 3
// baseline (418.275 us; speedup 1.0000x reference)
//
#include <hip/hip_runtime.h>
#include <cstdint>

#define D_FEAT 48

typedef float f4 __attribute__((ext_vector_type(4)));
typedef int   i4 __attribute__((ext_vector_type(4)));

// ---------------- K0: CSR row_ptr from sorted segment_ids (4 edges/thread) ----------------
__global__ __launch_bounds__(256) void k0_rowptr(const int* __restrict__ seg, int E, int N,
                                                 int* __restrict__ row_ptr) {
    int t  = blockIdx.x * blockDim.x + threadIdx.x;
    int e0 = t * 4;
    if (e0 >= E) return;

    i4 s4;
    if (e0 + 3 < E) {
        s4 = *(const i4*)(seg + e0);            // e0 multiple of 4 -> 16B aligned
    } else {
        #pragma unroll
        for (int k = 0; k < 4; ++k) s4[k] = (e0 + k < E) ? seg[e0 + k] : 0;
    }
    int sp = (e0 == 0) ? -1 : seg[e0 - 1];
    #pragma unroll
    for (int k = 0; k < 4; ++k) {
        int e = e0 + k;
        if (e >= E) break;
        int s = s4[k];
        for (int n = sp + 1; n <= s; ++n) row_ptr[n] = e;
        sp = s;
    }
    if (e0 + 4 >= E) {                          // thread containing edge E-1 fills the tail
        for (int n = sp + 1; n <= N; ++n) row_ptr[n] = E;
    }
}

// ---------------- K2: hot kernel — one wave per node, occupancy-capped ----------------
// Theory this round: previous k2 collapsed to ~1-2 waves/SIMD (register balloon from
// the f[8] batch under unbounded __launch_bounds__), serializing waves -> ~1.5 TB/s.
// Fixes: (a) __launch_bounds__(256,4) caps VGPR<=128 (>=16 waves/CU guaranteed),
// (b) batch shrunk to f[4] (same per-lane FMA order -> bit-identical numerics),
// (c) one wave per node -> 50000 waves of latency-hiding,
// (d) plain (cacheable) ft loads: ft is re-read every bench iteration and mostly
//     fits the 256 MB L3; nontemporal evict-first defeated that for zero gain.
// Inline exp + fused denominator (no k1, no den array, no atomics) as validated.
__global__ __launch_bounds__(256, 4) void k2_accum(
    const float* __restrict__ ft, const float* __restrict__ a,
    const int* __restrict__ row_ptr, float* __restrict__ out, int N)
{
    int lane = threadIdx.x & 63;
    int n = blockIdx.x * 4 + (threadIdx.x >> 6);
    if (n >= N) return;

    int lo  = row_ptr[n];        // two independent L2-hot loads, issued together
    int hi  = row_ptr[n + 1];
    int cnt = hi - lo;

    if (cnt <= 0) {              // empty segment: out is poisoned -> write 0
        if (lane < 12) {
            f4 z = {0.f, 0.f, 0.f, 0.f};
            __builtin_nontemporal_store(z, (f4*)(out + (size_t)n * D_FEAT + 4 * lane));
        }
        return;
    }

    int m    = lane % 12;
    int ecls = lane / 12;
    f4    acc  = {0.f, 0.f, 0.f, 0.f};
    float dsum = 0.0f;

    if (lane < 48) {
        const float* base = ft + (size_t)lo * D_FEAT + 4 * m;
        const float* ap   = a + lo;
        int ngroups = (cnt + 3) >> 2;
        for (int g = 0; g < ngroups; g += 4) {
            f4 f[4];
            #pragma unroll
            for (int k = 0; k < 4; ++k) {        // 4 independent 768-B wave loads
                int e  = (g + k) * 4 + ecls;
                int ec = min(e, cnt - 1);
                f[k] = *(const f4*)(base + (size_t)ec * D_FEAT);
            }
            float w[4];
            #pragma unroll
            for (int k = 0; k < 4; ++k) {        // a[] reads: ~128 B/node, L1/L2-hot
                int e  = (g + k) * 4 + ecls;
                int ec = min(e, cnt - 1);
                float wv = __expf(ap[ec]);
                w[k] = (e < cnt) ? wv : 0.0f;
            }
            #pragma unroll
            for (int k = 0; k < 4; ++k) {
                acc.x = fmaf(w[k], f[k].x, acc.x);
                acc.y = fmaf(w[k], f[k].y, acc.y);
                acc.z = fmaf(w[k], f[k].z, acc.z);
                acc.w = fmaf(w[k], f[k].w, acc.w);
                dsum += w[k];
            }
        }
    }

    // cross-class reduce (classes at lanes 0-11,12-23,24-35,36-47); all 64 lanes
    // execute so source lanes are active. Junk in lanes >=24 after step 1 is unread.
    f4 t; float td;
    t.x = __shfl(acc.x, lane + 24, 64); t.y = __shfl(acc.y, lane + 24, 64);
    t.z = __shfl(acc.z, lane + 24, 64); t.w = __shfl(acc.w, lane + 24, 64);
    td  = __shfl(dsum,  lane + 24, 64);
    acc.x += t.x; acc.y += t.y; acc.z += t.z; acc.w += t.w; dsum += td;
    t.x = __shfl(acc.x, lane + 12, 64); t.y = __shfl(acc.y, lane + 12, 64);
    t.z = __shfl(acc.z, lane + 12, 64); t.w = __shfl(acc.w, lane + 12, 64);
    td  = __shfl(dsum,  lane + 12, 64);
    acc.x += t.x; acc.y += t.y; acc.z += t.z; acc.w += t.w; dsum += td;

    if (lane < 12) {
        float inv = 1.0f / dsum;                 // cnt >= 1 -> dsum > 0
        f4 r = {acc.x * inv, acc.y * inv, acc.z * inv, acc.w * inv};
        __builtin_nontemporal_store(r, (f4*)(out + (size_t)n * D_FEAT + 4 * lane));
    }
}

extern "C" void kernel_launch(void* const* d_in, const int* in_sizes, int n_in,
                              void* d_out, int out_size, void* d_ws, size_t ws_size,
                              hipStream_t stream) {
    const float* a   = (const float*)d_in[0];
    const float* ft  = (const float*)d_in[1];
    const int*   seg = (const int*)d_in[2];
    int E = in_sizes[0];
    int N = out_size / D_FEAT;   // out_size is in ELEMENTS

    // ws layout: row_ptr (N+1 ints) only
    int* row_ptr = (int*)d_ws;

    int grid0 = (E / 4 + 255) / 256 + 1;   // 4 edges/thread
    int grid2 = (N + 3) / 4;               // one wave per node, 4 waves/block

    k0_rowptr<<<grid0, 256, 0, stream>>>(seg, E, N, row_ptr);
    k2_accum <<<grid2, 256, 0, stream>>>(ft, a, row_ptr, (float*)d_out, N);
}